// Round 1
// baseline (76.427 us; speedup 1.0000x reference)
//
#include <hip/hip_runtime.h>
#include <math.h>

#define THRESH_ 0.95f

// ws layout (float units):
// [0, 8192)            wc   : centered vocab [1024][8]
// [8192, 9216)         wstd : [1024]
// [9216, 271360)       hc   : [32768][8]  (pre-masked)
// [271360, 304128)     idx  : [32768] (int)

__global__ __launch_bounds__(256) void k0_vocab(const float* __restrict__ vocab,
                                                float* __restrict__ wc,
                                                float* __restrict__ wstd) {
    int v = blockIdx.x * 256 + threadIdx.x;
    if (v >= 1024) return;
    const float4* v4 = (const float4*)vocab + v * 2;
    float4 a = v4[0], b = v4[1];
    float w[8] = {a.x, a.y, a.z, a.w, b.x, b.y, b.z, b.w};
    float s = 0.f;
#pragma unroll
    for (int c = 0; c < 8; c++) s += w[c];
    float mean = s * 0.125f;
    float ss = 0.f;
    float wcv[8];
#pragma unroll
    for (int c = 0; c < 8; c++) { wcv[c] = w[c] - mean; ss += wcv[c] * wcv[c]; }
    float sd = sqrtf(ss * 0.125f);
    float4 o0 = {wcv[0], wcv[1], wcv[2], wcv[3]};
    float4 o1 = {wcv[4], wcv[5], wcv[6], wcv[7]};
    ((float4*)wc)[v * 2] = o0;
    ((float4*)wc)[v * 2 + 1] = o1;
    wstd[v] = sd;
}

// one block per batch row b; 1024 threads: t = part*128 + s  (part = v-chunk)
__global__ __launch_bounds__(1024) void k1_select(const float* __restrict__ X,
                                                  const float* __restrict__ wc,
                                                  const float* __restrict__ wstd,
                                                  float* __restrict__ hcw,
                                                  int* __restrict__ idxw) {
    __shared__ float xrow[1024];
    __shared__ float stb[1024];
    __shared__ int   sti[1024];
    __shared__ float stm[1024];
    __shared__ float tree[254]; // sum8[128] | sum16[64]@128 | sum32[32]@192 | sum64[16]@224 | sum128[8]@240 | sum256[4]@248 | sum512[2]@252

    int t = threadIdx.x;
    int b = blockIdx.x;
    int part = t >> 7;
    int s = t & 127;

    xrow[t] = X[b * 1024 + t];
    __syncthreads();

    // segment stats (each of the 8 part-threads for segment s redundantly computes)
    float seg[8];
#pragma unroll
    for (int c = 0; c < 8; c++) seg[c] = xrow[s * 8 + c];
    float sum = 0.f;
#pragma unroll
    for (int c = 0; c < 8; c++) sum += seg[c];
    float mean = sum * 0.125f;
    float segc[8];
    float ss = 0.f;
#pragma unroll
    for (int c = 0; c < 8; c++) { segc[c] = seg[c] - mean; ss += segc[c] * segc[c]; }
    float sstd = sqrtf(ss * 0.125f);

    // sequential select over this thread's contiguous v-chunk [part*128, part*128+128)
    float best = -INFINITY;
    int bi = -1;
    float m = 0.f;
    const float4* wc4 = (const float4*)wc;
    int vbase = part << 7;
    for (int i = 0; i < 128; i++) {
        int vu = __builtin_amdgcn_readfirstlane(vbase + i); // wave-uniform -> s_load
        float4 wa = wc4[vu * 2];
        float4 wb = wc4[vu * 2 + 1];
        float wsd = wstd[vu];
        float cov = segc[0] * wa.x + segc[1] * wa.y + segc[2] * wa.z + segc[3] * wa.w
                  + segc[4] * wb.x + segc[5] * wb.y + segc[6] * wb.z + segc[7] * wb.w;
        cov *= 0.125f;
        float denom = wsd * sstd;
        float c = (denom == 0.f) ? 0.f : cov / denom;
        float a = fabsf(c);
        if (a > THRESH_ && best < a) { best = c; bi = vbase + i; }
        m = fmaxf(m, a);
    }
    stb[t] = best;
    sti[t] = bi;
    stm[t] = m;
    if (t < 128) tree[t] = sum; // sum of 8 elements of segment t
    __syncthreads();

    // build sum tree (pairwise, matching Haar cascade structure)
    if (t < 64) tree[128 + t] = tree[2 * t] + tree[2 * t + 1];
    __syncthreads();
    if (t < 32) tree[192 + t] = tree[128 + 2 * t] + tree[128 + 2 * t + 1];
    __syncthreads();
    if (t < 16) tree[224 + t] = tree[192 + 2 * t] + tree[192 + 2 * t + 1];
    __syncthreads();
    if (t < 8) tree[240 + t] = tree[224 + 2 * t] + tree[224 + 2 * t + 1];
    __syncthreads();
    if (t < 4) tree[248 + t] = tree[240 + 2 * t] + tree[240 + 2 * t + 1];
    __syncthreads();
    if (t < 2) tree[252 + t] = tree[248 + 2 * t] + tree[248 + 2 * t + 1];
    __syncthreads();

    if (t < 128) {
        // ordered merge of the 8 v-chunk states for segment s = t
        float Bb = stb[t];
        int I = sti[t];
#pragma unroll
        for (int p = 1; p < 8; p++) {
            float yb = stb[p * 128 + t];
            int yi = sti[p * 128 + t];
            float ym = stm[p * 128 + t];
            bool take = (yi != -1) && (!(Bb > THRESH_) || (ym > Bb));
            if (take) { Bb = yb; I = yi; }
        }
        float mask = (I >= 0) ? 1.f : 0.f;

        // haar coefficients: hc[l] = 2^{-k/2} * (S_{2j} - S_{2j+1}), k = 10-l
        const int base[7] = {252, 248, 240, 224, 192, 128, 0};
        const float scl[7] = {0.03125f, 0.04419417382415922f, 0.0625f,
                              0.08838834764831843f, 0.125f,
                              0.17677669529663687f, 0.25f};
        float hcv[8];
#pragma unroll
        for (int l = 0; l < 7; l++) {
            int j = (t << l) >> 7;
            hcv[l] = scl[l] * (tree[base[l] + 2 * j] - tree[base[l] + 2 * j + 1]);
        }
        float s4a = seg[0] + seg[1] + seg[2] + seg[3];
        float s4b = seg[4] + seg[5] + seg[6] + seg[7];
        hcv[7] = 0.3535533905932738f * (s4a - s4b);

        int row = b * 128 + t;
#pragma unroll
        for (int l = 0; l < 8; l++) hcw[row * 8 + l] = hcv[l] * mask;
        idxw[row] = I;
    }
}

// output assembly: out[r,:] = pos[s] + mask*(word_emb[idx] + sum_l hc[l]*haar_emb[l])
__global__ __launch_bounds__(256) void k2_out(const float* __restrict__ word_emb,
                                              const float* __restrict__ haar_emb,
                                              const float* __restrict__ pos_emb,
                                              const float* __restrict__ hcw,
                                              const int* __restrict__ idxw,
                                              float* __restrict__ out) {
    __shared__ float4 he4[1536]; // haar_emb [8][768] as float4
    int t = threadIdx.x;
    const float4* hg = (const float4*)haar_emb;
    for (int i = t; i < 1536; i += 256) he4[i] = hg[i];
    __syncthreads();

    int wave = t >> 6, lane = t & 63;
    for (int rl = wave; rl < 16; rl += 4) {
        int r = __builtin_amdgcn_readfirstlane((int)blockIdx.x * 16 + rl);
        int iv = idxw[r];
        int s = r & 127;
        const float4* p4 = (const float4*)pos_emb + s * 192;
        float4* o4 = (float4*)out + (size_t)r * 192;
        if (iv >= 0) {
            float h[8];
#pragma unroll
            for (int l = 0; l < 8; l++) h[l] = hcw[r * 8 + l];
            const float4* w4 = (const float4*)word_emb + iv * 192;
            for (int c = lane; c < 192; c += 64) {
                float4 p = p4[c];
                float4 w = w4[c];
                float4 acc;
                acc.x = p.x + w.x; acc.y = p.y + w.y;
                acc.z = p.z + w.z; acc.w = p.w + w.w;
#pragma unroll
                for (int l = 0; l < 8; l++) {
                    float4 hv = he4[l * 192 + c];
                    acc.x += h[l] * hv.x; acc.y += h[l] * hv.y;
                    acc.z += h[l] * hv.z; acc.w += h[l] * hv.w;
                }
                o4[c] = acc;
            }
        } else {
            for (int c = lane; c < 192; c += 64) o4[c] = p4[c];
        }
    }
}

extern "C" void kernel_launch(void* const* d_in, const int* in_sizes, int n_in,
                              void* d_out, int out_size, void* d_ws, size_t ws_size,
                              hipStream_t stream) {
    const float* X        = (const float*)d_in[0];
    const float* vocab    = (const float*)d_in[1];
    const float* word_emb = (const float*)d_in[2];
    const float* haar_emb = (const float*)d_in[3];
    const float* pos_emb  = (const float*)d_in[4];
    float* out = (float*)d_out;

    float* wsf  = (float*)d_ws;
    float* wc   = wsf;
    float* wstd = wsf + 8192;
    float* hcw  = wsf + 9216;
    int*   idxw = (int*)(wsf + 9216 + 262144);

    hipLaunchKernelGGL(k0_vocab, dim3(4), dim3(256), 0, stream, vocab, wc, wstd);
    hipLaunchKernelGGL(k1_select, dim3(256), dim3(1024), 0, stream, X, wc, wstd, hcw, idxw);
    hipLaunchKernelGGL(k2_out, dim3(2048), dim3(256), 0, stream,
                       word_emb, haar_emb, pos_emb, hcw, idxw, out);
}

// Round 2
// 62.597 us; speedup vs baseline: 1.2209x; 1.2209x over previous
//
#include <hip/hip_runtime.h>
#include <math.h>

#define THRESH_ 0.95f

// ws layout (float units):
// [0, 8192)            wc   : centered vocab [1024][8]
// [8192, 9216)         wstd : [1024]
// [9216, 271360)       hc   : [32768][8]  (pre-masked)
// [271360, 304128)     idx  : [32768] (int)

__global__ __launch_bounds__(256) void k0_vocab(const float* __restrict__ vocab,
                                                float* __restrict__ wc,
                                                float* __restrict__ wstd) {
    int v = blockIdx.x * 256 + threadIdx.x;
    if (v >= 1024) return;
    const float4* v4 = (const float4*)vocab + v * 2;
    float4 a = v4[0], b = v4[1];
    float w[8] = {a.x, a.y, a.z, a.w, b.x, b.y, b.z, b.w};
    float s = 0.f;
#pragma unroll
    for (int c = 0; c < 8; c++) s += w[c];
    float mean = s * 0.125f;
    float ss = 0.f;
    float wcv[8];
#pragma unroll
    for (int c = 0; c < 8; c++) { wcv[c] = w[c] - mean; ss += wcv[c] * wcv[c]; }
    float sd = sqrtf(ss * 0.125f);
    float4 o0 = {wcv[0], wcv[1], wcv[2], wcv[3]};
    float4 o1 = {wcv[4], wcv[5], wcv[6], wcv[7]};
    ((float4*)wc)[v * 2] = o0;
    ((float4*)wc)[v * 2 + 1] = o1;
    wstd[v] = sd;
}

// one block per batch row b; 1024 threads: t = part*128 + s  (part = v-chunk)
__global__ __launch_bounds__(1024) void k1_select(const float* __restrict__ X,
                                                  const float* __restrict__ wc,
                                                  const float* __restrict__ wstd,
                                                  float* __restrict__ hcw,
                                                  int* __restrict__ idxw) {
    __shared__ float xrow[1024];
    __shared__ float stb[1024];
    __shared__ int   sti[1024];
    __shared__ float stm[1024];
    __shared__ float tree[254]; // sum8[128] | sum16[64]@128 | sum32[32]@192 | sum64[16]@224 | sum128[8]@240 | sum256[4]@248 | sum512[2]@252

    int t = threadIdx.x;
    int b = blockIdx.x;
    int part = t >> 7;
    int s = t & 127;

    xrow[t] = X[b * 1024 + t];
    __syncthreads();

    // segment stats (each of the 8 part-threads for segment s redundantly computes)
    float seg[8];
#pragma unroll
    for (int c = 0; c < 8; c++) seg[c] = xrow[s * 8 + c];
    float sum = 0.f;
#pragma unroll
    for (int c = 0; c < 8; c++) sum += seg[c];
    float mean = sum * 0.125f;
    float segc[8];
    float ss = 0.f;
#pragma unroll
    for (int c = 0; c < 8; c++) { segc[c] = seg[c] - mean; ss += segc[c] * segc[c]; }
    float sstd = sqrtf(ss * 0.125f);

    // scan this thread's contiguous v-chunk; division only in the rare pass path.
    // RN32(|cov|/denom) > 0.95f  <=>  (double)|cov| >= MID * (double)denom,
    // MID = 0.95f + 2^-25 (exact; tie rounds to even neighbor 0x3F733334 > 0.95f).
    float best = -INFINITY;
    int bi = -1;
    float m = 0.f;  // max |corr| over PASSING elements only (sufficient for merge)
    const float4* wc4 = (const float4*)wc;
    int vbase = __builtin_amdgcn_readfirstlane(part << 7);
    const double MID = 0x1.E66667p-1;
#pragma unroll 4
    for (int i = 0; i < 128; i++) {
        int vu = vbase + i;  // wave-uniform -> scalar loads
        float4 wa = wc4[vu * 2];
        float4 wb = wc4[vu * 2 + 1];
        float wsd = wstd[vu];
        float cov = segc[0] * wa.x + segc[1] * wa.y + segc[2] * wa.z + segc[3] * wa.w
                  + segc[4] * wb.x + segc[5] * wb.y + segc[6] * wb.z + segc[7] * wb.w;
        cov *= 0.125f;
        float denom = wsd * sstd;
        if ((double)fabsf(cov) >= MID * (double)denom) {
            // rare path: exact reference semantics (fp32 IEEE divide)
            float c = (denom == 0.f) ? 0.f : cov / denom;
            float a = fabsf(c);
            if (a > THRESH_ && best < a) { best = c; bi = vu; }
            m = fmaxf(m, a);
        }
    }
    stb[t] = best;
    sti[t] = bi;
    stm[t] = m;
    if (t < 128) tree[t] = sum; // sum of 8 elements of segment t
    __syncthreads();

    // build sum tree (pairwise, matching Haar cascade structure)
    if (t < 64) tree[128 + t] = tree[2 * t] + tree[2 * t + 1];
    __syncthreads();
    if (t < 32) tree[192 + t] = tree[128 + 2 * t] + tree[128 + 2 * t + 1];
    __syncthreads();
    if (t < 16) tree[224 + t] = tree[192 + 2 * t] + tree[192 + 2 * t + 1];
    __syncthreads();
    if (t < 8) tree[240 + t] = tree[224 + 2 * t] + tree[224 + 2 * t + 1];
    __syncthreads();
    if (t < 4) tree[248 + t] = tree[240 + 2 * t] + tree[240 + 2 * t + 1];
    __syncthreads();
    if (t < 2) tree[252 + t] = tree[248 + 2 * t] + tree[248 + 2 * t + 1];
    __syncthreads();

    if (t < 128) {
        // ordered merge of the 8 v-chunk states for segment s = t
        float Bb = stb[t];
        int I = sti[t];
#pragma unroll
        for (int p = 1; p < 8; p++) {
            float yb = stb[p * 128 + t];
            int yi = sti[p * 128 + t];
            float ym = stm[p * 128 + t];
            bool take = (yi != -1) && (!(Bb > THRESH_) || (ym > Bb));
            if (take) { Bb = yb; I = yi; }
        }
        float mask = (I >= 0) ? 1.f : 0.f;

        // haar coefficients: hc[l] = 2^{-k/2} * (S_{2j} - S_{2j+1}), k = 10-l
        const int base[7] = {252, 248, 240, 224, 192, 128, 0};
        const float scl[7] = {0.03125f, 0.04419417382415922f, 0.0625f,
                              0.08838834764831843f, 0.125f,
                              0.17677669529663687f, 0.25f};
        float hcv[8];
#pragma unroll
        for (int l = 0; l < 7; l++) {
            int j = (t << l) >> 7;
            hcv[l] = scl[l] * (tree[base[l] + 2 * j] - tree[base[l] + 2 * j + 1]);
        }
        float s4a = seg[0] + seg[1] + seg[2] + seg[3];
        float s4b = seg[4] + seg[5] + seg[6] + seg[7];
        hcv[7] = 0.3535533905932738f * (s4a - s4b);

        int row = b * 128 + t;
#pragma unroll
        for (int l = 0; l < 8; l++) hcw[row * 8 + l] = hcv[l] * mask;
        idxw[row] = I;
    }
}

// output assembly: out[r,:] = pos[s] + mask*(word_emb[idx] + sum_l hc[l]*haar_emb[l])
// haar_emb slice lives in 96 VGPRs per thread (no LDS). 32 rows per block.
__global__ __launch_bounds__(256) void k2_out(const float* __restrict__ word_emb,
                                              const float* __restrict__ haar_emb,
                                              const float* __restrict__ pos_emb,
                                              const float* __restrict__ hcw,
                                              const int* __restrict__ idxw,
                                              float* __restrict__ out) {
    int t = threadIdx.x;
    int lane = t & 63, wave = t >> 6;

    // each lane owns float4-columns {lane, lane+64, lane+128}; preload its
    // 3x8 slice of haar_emb into registers (static indexing only)
    float4 he_r[3][8];
    const float4* hg = (const float4*)haar_emb;
#pragma unroll
    for (int cb = 0; cb < 3; cb++)
#pragma unroll
        for (int l = 0; l < 8; l++)
            he_r[cb][l] = hg[l * 192 + cb * 64 + lane];

    int rbase = (int)blockIdx.x * 32 + wave * 8;
    for (int k = 0; k < 8; k++) {
        int r = rbase + k;          // wave-uniform
        int iv = idxw[r];           // uniform -> scalar load + scalar branch
        int s = r & 127;
        const float4* p4 = (const float4*)pos_emb + s * 192;
        float4* o4 = (float4*)out + (size_t)r * 192;
        if (iv >= 0) {
            float h[8];
#pragma unroll
            for (int l = 0; l < 8; l++) h[l] = hcw[r * 8 + l];  // uniform -> s_load
            const float4* w4 = (const float4*)word_emb + iv * 192;
#pragma unroll
            for (int cb = 0; cb < 3; cb++) {
                int c = cb * 64 + lane;
                float4 p = p4[c];
                float4 w = w4[c];
                float4 acc;
                acc.x = p.x + w.x; acc.y = p.y + w.y;
                acc.z = p.z + w.z; acc.w = p.w + w.w;
#pragma unroll
                for (int l = 0; l < 8; l++) {
                    acc.x += h[l] * he_r[cb][l].x;
                    acc.y += h[l] * he_r[cb][l].y;
                    acc.z += h[l] * he_r[cb][l].z;
                    acc.w += h[l] * he_r[cb][l].w;
                }
                o4[c] = acc;
            }
        } else {
#pragma unroll
            for (int cb = 0; cb < 3; cb++) {
                int c = cb * 64 + lane;
                o4[c] = p4[c];
            }
        }
    }
}

extern "C" void kernel_launch(void* const* d_in, const int* in_sizes, int n_in,
                              void* d_out, int out_size, void* d_ws, size_t ws_size,
                              hipStream_t stream) {
    const float* X        = (const float*)d_in[0];
    const float* vocab    = (const float*)d_in[1];
    const float* word_emb = (const float*)d_in[2];
    const float* haar_emb = (const float*)d_in[3];
    const float* pos_emb  = (const float*)d_in[4];
    float* out = (float*)d_out;

    float* wsf  = (float*)d_ws;
    float* wc   = wsf;
    float* wstd = wsf + 8192;
    float* hcw  = wsf + 9216;
    int*   idxw = (int*)(wsf + 9216 + 262144);

    hipLaunchKernelGGL(k0_vocab, dim3(4), dim3(256), 0, stream, vocab, wc, wstd);
    hipLaunchKernelGGL(k1_select, dim3(256), dim3(1024), 0, stream, X, wc, wstd, hcw, idxw);
    hipLaunchKernelGGL(k2_out, dim3(1024), dim3(256), 0, stream,
                       word_emb, haar_emb, pos_emb, hcw, idxw, out);
}